// Round 4
// baseline (45.564 us; speedup 1.0000x reference)
//
#include <hip/hip_runtime.h>

// Shapes fixed by setup_inputs(): b=8, t=128, k=128, h=4, m=t-1=127.
#define KD 128
#define NH 4
#define MM 127
#define NPRE 516    // Wct precompute blocks (one per Wv row)

// workspace layout (float offsets)
#define OFF_WC 0            // [4][256][128]  Wct[h][c][dd]  (c-major)
#define OFF_C  131072       // [1024][512]    weighted kv sums per (bt, h*128+d)

// ---------------------------------------------------------------------------
// Kernel 1 (fused, block-specialized):
//   blocks 0..515     : Wct[h][c][dd] precompute (value rows of W1|W2)
//   blocks 516..1539  : per-(b,t) attention c-sum, with per-WG W1S recompute
// (q/W2/bias terms are constant in m -> cancel in softmax -> dropped.)
// ---------------------------------------------------------------------------
__global__ __launch_bounds__(256, 4)
void attn_fused(const float* __restrict__ kv_x,
                const float* __restrict__ Wk,
                const float* __restrict__ Wq,
                const float* __restrict__ Wv,
                float* __restrict__ ws) {
    const int bid = blockIdx.x;
    const int tid = threadIdx.x;

    if (bid < NPRE) {
        // ---- Wct precompute: W1[o][k]=sum_j Wv[o][j]*Wk[j][k], W2 similarly
        int o = bid;
        int h = o / 129, r = o - h * 129;
        if (r == 0) return;              // score rows handled inside attn WGs
        int dd = r - 1;
        int which = tid >> 7, k = tid & 127;
        const float* W = which ? Wq : Wk;
        const float* wvrow = Wv + (size_t)o * 256 + which * 128;
        float acc = 0.f;
        #pragma unroll 8
        for (int j = 0; j < 128; ++j)
            acc += wvrow[j] * W[j * 128 + k];
        ws[OFF_WC + (size_t)(h * 256 + which * 128 + k) * 128 + dd] = acc;
        return;
    }

    // ---------------- attention path ----------------
    __shared__ float sW1s[NH * KD];    // 4 score-projection rows (2 KB)
    __shared__ float ssc[512];         // scores [m][h]
    __shared__ float swt[512];         // softmax weights [m][h]
    __shared__ float cpart[8][512];    // per-group c partials (16 KB)

    const int bt = bid - NPRE;
    const int dq = tid & 31;           // d-quad (d = dq*4+j)
    const int g  = tid >> 5;           // 32-lane group 0..7

    // issue kv loads FIRST (HBM latency hides under W1S compute via TLP)
    const float4* src = (const float4*)(kv_x + (size_t)bt * MM * KD);
    float4 kvr[16];
    #pragma unroll
    for (int k = 0; k < 16; ++k) {
        int idx = tid + k * 256;
        kvr[k] = (idx < MM * 32) ? src[idx] : make_float4(0.f, 0.f, 0.f, 0.f);
    }

    // per-WG W1S: sW1s[h][k] = sum_j Wv[129h*256+j] * Wk[j*128+k]
    {
        int h0 = tid >> 7;             // 0/1; also handle h0+2
        int k  = tid & 127;
        const float* wv0 = Wv + (size_t)(129 * h0) * 256;
        const float* wv2 = Wv + (size_t)(129 * (h0 + 2)) * 256;
        float a0 = 0.f, a1 = 0.f;
        #pragma unroll 8
        for (int j = 0; j < 128; ++j) {
            float wk = Wk[j * 128 + k];
            a0 += wv0[j] * wk;
            a1 += wv2[j] * wk;
        }
        sW1s[h0 * 128 + k]       = a0;
        sW1s[(h0 + 2) * 128 + k] = a1;
    }
    __syncthreads();

    float4 w1s[NH];
    #pragma unroll
    for (int h = 0; h < NH; ++h)
        w1s[h] = *(const float4*)&sW1s[h * KD + dq * 4];

    // ---- scores: per row, 4-head partials + head-splitting butterfly
    const int bit4 = (tid >> 4) & 1;
    const int bit3 = (tid >> 3) & 1;
    const int myh  = bit4 * 2 + bit3;
    #pragma unroll
    for (int k = 0; k < 16; ++k) {
        float4 kv4 = kvr[k];
        float p0 = kv4.x*w1s[0].x + kv4.y*w1s[0].y + kv4.z*w1s[0].z + kv4.w*w1s[0].w;
        float p1 = kv4.x*w1s[1].x + kv4.y*w1s[1].y + kv4.z*w1s[1].z + kv4.w*w1s[1].w;
        float p2 = kv4.x*w1s[2].x + kv4.y*w1s[2].y + kv4.z*w1s[2].z + kv4.w*w1s[2].w;
        float p3 = kv4.x*w1s[3].x + kv4.y*w1s[3].y + kv4.z*w1s[3].z + kv4.w*w1s[3].w;
        float x = bit4 ? p0 : p2;
        float y = bit4 ? p1 : p3;
        float a = (bit4 ? p2 : p0) + __shfl_xor(x, 16);
        float b = (bit4 ? p3 : p1) + __shfl_xor(y, 16);
        float z = bit3 ? a : b;
        float v = (bit3 ? b : a) + __shfl_xor(z, 8);
        v += __shfl_xor(v, 4);
        v += __shfl_xor(v, 2);
        v += __shfl_xor(v, 1);
        int m = g + 8 * k;
        if ((tid & 7) == 0 && m < MM) ssc[m * 4 + myh] = v;
    }
    __syncthreads();

    // ---- softmax over m: one wave per head
    {
        int h = tid >> 6, lane = tid & 63;
        float v0 = ssc[lane * 4 + h];
        bool has1 = (lane + 64) < MM;
        float v1 = has1 ? ssc[(lane + 64) * 4 + h] : -1e30f;
        float mx = fmaxf(v0, v1);
        #pragma unroll
        for (int off = 32; off; off >>= 1) mx = fmaxf(mx, __shfl_xor(mx, off));
        float e0 = __expf(v0 - mx);
        float e1 = has1 ? __expf(v1 - mx) : 0.f;
        float s = e0 + e1;
        #pragma unroll
        for (int off = 32; off; off >>= 1) s += __shfl_xor(s, off);
        float inv = 1.f / s;
        swt[lane * 4 + h] = e0 * inv;
        swt[(lane + 64) * 4 + h] = has1 ? e1 * inv : 0.f;   // m=127 pad -> 0
    }
    __syncthreads();

    // ---- weighted sum into registers over my d-quad
    float4 cacc[NH];
    #pragma unroll
    for (int h = 0; h < NH; ++h) cacc[h] = make_float4(0.f, 0.f, 0.f, 0.f);
    #pragma unroll
    for (int k = 0; k < 16; ++k) {
        int m = g + 8 * k;
        float4 wv  = *(const float4*)&swt[m * 4];
        float4 kv4 = kvr[k];
        cacc[0].x += wv.x*kv4.x; cacc[0].y += wv.x*kv4.y; cacc[0].z += wv.x*kv4.z; cacc[0].w += wv.x*kv4.w;
        cacc[1].x += wv.y*kv4.x; cacc[1].y += wv.y*kv4.y; cacc[1].z += wv.y*kv4.z; cacc[1].w += wv.y*kv4.w;
        cacc[2].x += wv.z*kv4.x; cacc[2].y += wv.z*kv4.y; cacc[2].z += wv.z*kv4.z; cacc[2].w += wv.z*kv4.w;
        cacc[3].x += wv.w*kv4.x; cacc[3].y += wv.w*kv4.y; cacc[3].z += wv.w*kv4.z; cacc[3].w += wv.w*kv4.w;
    }
    #pragma unroll
    for (int h = 0; h < NH; ++h)
        *(float4*)&cpart[g][h * KD + dq * 4] = cacc[h];
    __syncthreads();

    // ---- reduce 8 group-partials, write c (coalesced)
    float* cdst = ws + OFF_C + (size_t)bt * 512;
    #pragma unroll
    for (int rep = 0; rep < 2; ++rep) {
        int o = tid + rep * 256;
        float s = 0.f;
        #pragma unroll
        for (int gg = 0; gg < 8; ++gg) s += cpart[gg][o];
        cdst[o] = s;
    }
}

// ---------------------------------------------------------------------------
// Kernel 2: out[r][h*128+dd] = sum_c A_h[r][c]*Wct[h][c][dd] + bv,  K=256,
// A_h[r] = [ c[r][h][0:128] | q_x[r][0:128] ].
// BM=32 x BN=64, BK=64, 256 WGs, 2x4 register blocking, b64/b128 LDS reads.
// ---------------------------------------------------------------------------
#define BM 32
#define BN 64
#define BK 64
#define AP 34   // sAT row pad (even -> b64-aligned, 2-way max)
#define BP 68   // sB row pad (16B-aligned float4 reads, conflict-free)

__global__ __launch_bounds__(256, 2)
void proj_out(const float* __restrict__ q_x,
              const float* __restrict__ bv,
              const float* __restrict__ ws,
              float* __restrict__ out) {
    __shared__ float sAT[BK][AP];   // A transposed [c][r]  (8.7 KB)
    __shared__ float sB[BK][BP];    // B [c][dd]            (17.4 KB)

    const int r0  = blockIdx.x * BM;
    const int dd0 = blockIdx.y * BN;
    const int h   = blockIdx.z;
    const int tid = threadIdx.x;
    const int tx  = tid & 15;       // 16 col-groups x 4 cols
    const int ty  = tid >> 4;       // 16 row-groups x 2 rows
    const float* cmat = ws + OFF_C;
    const float* Wct  = ws + OFF_WC;

    float acc[2][4];
    #pragma unroll
    for (int i = 0; i < 2; ++i)
        #pragma unroll
        for (int j = 0; j < 4; ++j) acc[i][j] = 0.f;

    for (int ks = 0; ks < 4; ++ks) {
        int kk0 = ks * BK;
        // stage A transposed: 32 rows x 64 c
        const float* Abase; int Astride;
        if (kk0 < 128) { Abase = cmat + h * KD + kk0; Astride = 512; }
        else           { Abase = q_x + (kk0 - 128);   Astride = KD;  }
        #pragma unroll
        for (int i = 0; i < 2; ++i) {
            int idx = tid + i * 256;         // 0..511
            int r = idx >> 4, c4 = idx & 15;
            float4 v = *(const float4*)(Abase + (size_t)(r0 + r) * Astride + c4 * 4);
            sAT[c4 * 4 + 0][r] = v.x;
            sAT[c4 * 4 + 1][r] = v.y;
            sAT[c4 * 4 + 2][r] = v.z;
            sAT[c4 * 4 + 3][r] = v.w;
        }
        // stage B: 64 c-rows x 64 dd, direct coalesced copy
        #pragma unroll
        for (int i = 0; i < 4; ++i) {
            int idx = tid + i * 256;         // 0..1023
            int c = idx >> 4, d4 = idx & 15;
            *(float4*)&sB[c][d4 * 4] =
                *(const float4*)(Wct + (size_t)(h * 256 + kk0 + c) * 128 + dd0 + d4 * 4);
        }
        __syncthreads();
        #pragma unroll 8
        for (int c = 0; c < BK; ++c) {
            float2 a  = *(const float2*)&sAT[c][ty * 2];
            float4 b4 = *(const float4*)&sB[c][tx * 4];
            acc[0][0] += a.x * b4.x; acc[0][1] += a.x * b4.y;
            acc[0][2] += a.x * b4.z; acc[0][3] += a.x * b4.w;
            acc[1][0] += a.y * b4.x; acc[1][1] += a.y * b4.y;
            acc[1][2] += a.y * b4.z; acc[1][3] += a.y * b4.w;
        }
        __syncthreads();
    }
    // epilogue: + bias, coalesced float4 stores
    float bb[4];
    #pragma unroll
    for (int j = 0; j < 4; ++j) bb[j] = bv[h * 129 + 1 + dd0 + tx * 4 + j];
    #pragma unroll
    for (int i = 0; i < 2; ++i) {
        float4 v;
        v.x = acc[i][0] + bb[0];
        v.y = acc[i][1] + bb[1];
        v.z = acc[i][2] + bb[2];
        v.w = acc[i][3] + bb[3];
        *(float4*)(out + (size_t)(r0 + ty * 2 + i) * 512 + h * KD + dd0 + tx * 4) = v;
    }
}

extern "C" void kernel_launch(void* const* d_in, const int* in_sizes, int n_in,
                              void* d_out, int out_size, void* d_ws, size_t ws_size,
                              hipStream_t stream) {
    const float* q_x  = (const float*)d_in[0];
    const float* kv_x = (const float*)d_in[1];
    const float* Wk   = (const float*)d_in[2];
    const float* Wq   = (const float*)d_in[3];
    const float* Wv   = (const float*)d_in[4];
    const float* bv   = (const float*)d_in[5];
    float* out = (float*)d_out;
    float* ws  = (float*)d_ws;

    int bt = in_sizes[0] / KD;   // 1024

    hipLaunchKernelGGL(attn_fused, dim3(NPRE + bt), dim3(256), 0, stream,
                       kv_x, Wk, Wq, Wv, ws);
    hipLaunchKernelGGL(proj_out, dim3(bt / BM, KD / BN, NH), dim3(256), 0, stream,
                       q_x, bv, ws, out);
}